// Round 2
// baseline (236.065 us; speedup 1.0000x reference)
//
#include <hip/hip_runtime.h>
#include <hip/hip_bf16.h>
#include <cstdint>

typedef short short8 __attribute__((ext_vector_type(8)));
typedef float f32x4 __attribute__((ext_vector_type(4)));

// Problem constants
#define D_MODEL 1024
#define K_DIM   512      // d_code
#define T_CODE  2048
#define T_FULL  4096
#define OUT0_OFF 0
#define OUT0_SZ  (2*4096*1024)      // 8388608
#define OUT1_OFF OUT0_SZ            // 8388608
#define OUT1_SZ  (2*4096*64)        // 524288
#define OUT2_OFF (OUT0_SZ + OUT1_SZ) // 8912896

__device__ __forceinline__ unsigned short f2bf(float f) {
    unsigned u = __float_as_uint(f);
    unsigned r = (u + 0x7FFFu + ((u >> 16) & 1u)) >> 16;
    return (unsigned short)r;
}

// ---------------------------------------------------------------------------
// Kernel 1: per-batch bias row: bias[b][d] = b[d] + cond[b]@W_cond + spk[b]@W_spk
// 2048 threads total (2 batches x 1024 d). W reads coalesced across d.
// ---------------------------------------------------------------------------
__global__ __launch_bounds__(256) void bias_kernel(
    const float* __restrict__ cond, const float* __restrict__ spk,
    const float* __restrict__ W, const float* __restrict__ bvec,
    float* __restrict__ bias)
{
    int tid = blockIdx.x * 256 + threadIdx.x;   // 0..2047
    int b = tid >> 10;
    int d = tid & 1023;
    const float* condb = cond + b * 512;
    const float* spkb  = spk + b * 192;
    float acc = bvec[d];
    #pragma unroll 4
    for (int c = 0; c < 512; ++c)
        acc = fmaf(condb[c], W[(size_t)c * 1024 + d], acc);
    #pragma unroll 4
    for (int s = 0; s < 192; ++s)
        acc = fmaf(spkb[s], W[(size_t)(1024 + s) * 1024 + d], acc);
    bias[tid] = acc;
}

// ---------------------------------------------------------------------------
// Kernel 2: transpose W_code (rows 512..1023 of W, [512][1024] f32)
// into Wt bf16 [1024][512]  (n-major, k contiguous) for coalesced B staging.
// ---------------------------------------------------------------------------
__global__ __launch_bounds__(256) void transpose_kernel(
    const float* __restrict__ W, unsigned short* __restrict__ Wt)
{
    __shared__ float tile[32][33];
    int k0 = blockIdx.x * 32;   // 16 blocks over K=512
    int n0 = blockIdx.y * 32;   // 32 blocks over N=1024
    int lx = threadIdx.x & 31;
    int ly = threadIdx.x >> 5;  // 0..7
    #pragma unroll
    for (int rr = 0; rr < 32; rr += 8)
        tile[ly + rr][lx] = W[(size_t)(512 + k0 + ly + rr) * 1024 + n0 + lx];
    __syncthreads();
    #pragma unroll
    for (int rr = 0; rr < 32; rr += 8) {
        int n = n0 + ly + rr;
        int k = k0 + lx;
        Wt[(size_t)n * 512 + k] = f2bf(tile[lx][ly + rr]);
    }
}

// ---------------------------------------------------------------------------
// Kernel 3: rope.  out1[c][t][2k] = out1[c][t][2k+1] = cos/sin(t * theta_k)
// f64 sincos for accuracy vs numpy ref; tiny kernel (262144 threads).
// ---------------------------------------------------------------------------
__global__ __launch_bounds__(256) void rope_kernel(float* __restrict__ out1)
{
    int tid = blockIdx.x * 256 + threadIdx.x;   // 0..262143
    int kk = tid & 31;
    int t  = (tid >> 5) & 4095;
    int c  = tid >> 17;
    // theta = 10000^{-2k/64} = 2^{-k * log2(10000)/32}
    double theta = exp2(-(double)kk * 0.41524101186092028);
    double a = (double)t * theta;
    double v = c ? sin(a) : cos(a);
    float vf = (float)v;
    float2 w; w.x = vf; w.y = vf;
    *(float2*)&out1[(size_t)(c * 4096 + t) * 64 + kk * 2] = w;
}

// ---------------------------------------------------------------------------
// Kernel 4: mask.  out2[i*4096 + j] = (float)(j/24 - i/24). float4 stores.
// ---------------------------------------------------------------------------
__global__ __launch_bounds__(256) void mask_kernel(float* __restrict__ out2)
{
    const int total4 = (4096 * 4096) / 4;       // 4194304 float4
    int stride = gridDim.x * blockDim.x;
    for (int q = blockIdx.x * blockDim.x + threadIdx.x; q < total4; q += stride) {
        int i = q >> 10;            // row (1024 float4 per row)
        int j = (q & 1023) << 2;    // col base
        int bi = i / 24;
        float4 v;
        v.x = (float)((j    ) / 24 - bi);
        v.y = (float)((j + 1) / 24 - bi);
        v.z = (float)((j + 2) / 24 - bi);
        v.w = (float)((j + 3) / 24 - bi);
        ((float4*)out2)[q] = v;
    }
}

// ---------------------------------------------------------------------------
// Kernel 5: GEMM.  out0[(b, 2u)][n] = out0[(b, 2u+1)][n]
//                = embed_table[code[b,u]] @ W_code[:, n] + bias[b][n]
// M = 4096 (gathered rows), N = 1024, K = 512.
// 128x128 tile, BK=64, 4 waves (2x2), 16x16x32 bf16 MFMA, XOR-swizzled LDS.
// ---------------------------------------------------------------------------
__global__ __launch_bounds__(256) void gemm_kernel(
    const float* __restrict__ embed, const int* __restrict__ code,
    const unsigned short* __restrict__ Wt, const float* __restrict__ bias,
    float* __restrict__ out0)
{
    __shared__ short8 AsV[128 * 64 / 8];   // A: [m][k] bf16, swizzled
    __shared__ short8 BsV[128 * 64 / 8];   // B: [n][k] bf16, swizzled
    unsigned short* As = (unsigned short*)AsV;
    unsigned short* Bs = (unsigned short*)BsV;

    const int tid = threadIdx.x;
    const int bm = blockIdx.x;   // 0..31  (M tiles)
    const int bn = blockIdx.y;   // 0..7   (N tiles)
    const int lane = tid & 63;
    const int wid = tid >> 6;
    const int wr = wid >> 1;     // 0..1
    const int wc = wid & 1;      // 0..1
    const int l15 = lane & 15;
    const int l4  = lane >> 4;   // 0..3

    f32x4 acc[4][4];
    #pragma unroll
    for (int i = 0; i < 4; ++i)
        #pragma unroll
        for (int j = 0; j < 4; ++j)
            acc[i][j] = (f32x4){0.f, 0.f, 0.f, 0.f};

    // Staging assignment: 1024 16B-chunks per tile, 4 per thread.
    // ch = i*256 + tid; row r = ch>>3 (8 chunks of 8 elems per 64-elem row);
    // kc = (ch&7)*8. LDS dst swizzle: k ^= (r&7)<<3 (16B-aligned XOR).
    long a_off[4]; long b_off[4]; int dst[4];
    #pragma unroll
    for (int i = 0; i < 4; ++i) {
        int ch = i * 256 + tid;
        int r  = ch >> 3;
        int kc = (ch & 7) * 8;
        int cv = code[bm * 128 + r];
        a_off[i] = (long)cv * 512 + kc;
        b_off[i] = (long)(bn * 128 + r) * 512 + kc;
        dst[i]   = r * 64 + (kc ^ ((r & 7) << 3));
    }

    for (int kt = 0; kt < 512; kt += 64) {
        __syncthreads();
        // stage A: gather f32 embed rows -> bf16 LDS
        #pragma unroll
        for (int i = 0; i < 4; ++i) {
            const float* s = embed + a_off[i] + kt;
            float4 f0 = *(const float4*)s;
            float4 f1 = *(const float4*)(s + 4);
            short8 v;
            v[0] = (short)f2bf(f0.x); v[1] = (short)f2bf(f0.y);
            v[2] = (short)f2bf(f0.z); v[3] = (short)f2bf(f0.w);
            v[4] = (short)f2bf(f1.x); v[5] = (short)f2bf(f1.y);
            v[6] = (short)f2bf(f1.z); v[7] = (short)f2bf(f1.w);
            *(short8*)&As[dst[i]] = v;
        }
        // stage B: pre-transposed bf16 rows, 16B coalesced
        #pragma unroll
        for (int i = 0; i < 4; ++i) {
            short8 v = *(const short8*)&Wt[b_off[i] + kt];
            *(short8*)&Bs[dst[i]] = v;
        }
        __syncthreads();
        // compute: 2 k-frags x 4x4 fragments = 32 MFMA per K-step
        #pragma unroll
        for (int ks = 0; ks < 2; ++ks) {
            const int kb = ks * 32 + l4 * 8;
            short8 af[4], bf[4];
            #pragma unroll
            for (int mi = 0; mi < 4; ++mi) {
                int r = wr * 64 + mi * 16 + l15;
                af[mi] = *(const short8*)&As[r * 64 + (kb ^ ((r & 7) << 3))];
            }
            #pragma unroll
            for (int ni = 0; ni < 4; ++ni) {
                int n = wc * 64 + ni * 16 + l15;
                bf[ni] = *(const short8*)&Bs[n * 64 + (kb ^ ((n & 7) << 3))];
            }
            #pragma unroll
            for (int mi = 0; mi < 4; ++mi)
                #pragma unroll
                for (int ni = 0; ni < 4; ++ni)
                    acc[mi][ni] = __builtin_amdgcn_mfma_f32_16x16x32_bf16(
                        af[mi], bf[ni], acc[mi][ni], 0, 0, 0);
        }
    }

    // Epilogue: C/D layout col = lane&15, row = (lane>>4)*4 + j (m89-verified).
    // Each GEMM row m -> out rows t = 2u, 2u+1 (repeat along time).
    const int b = bm >> 4;                  // 16 M-tiles per batch
    const float* biasb = bias + b * 1024;
    #pragma unroll
    for (int ni = 0; ni < 4; ++ni) {
        const int n = bn * 128 + wc * 64 + ni * 16 + l15;
        const float bv = biasb[n];
        #pragma unroll
        for (int mi = 0; mi < 4; ++mi) {
            const int mbase = bm * 128 + wr * 64 + mi * 16 + l4 * 4;
            #pragma unroll
            for (int j = 0; j < 4; ++j) {
                const int u = (mbase + j) & 2047;
                const size_t o = ((size_t)(b * 4096 + 2 * u)) * 1024 + n;
                const float v = acc[mi][ni][j] + bv;
                out0[o] = v;
                out0[o + 1024] = v;
            }
        }
    }
}

// ---------------------------------------------------------------------------
extern "C" void kernel_launch(void* const* d_in, const int* in_sizes, int n_in,
                              void* d_out, int out_size, void* d_ws, size_t ws_size,
                              hipStream_t stream) {
    const float* cond  = (const float*)d_in[0];   // (2,1,512)
    const float* spk   = (const float*)d_in[1];   // (2,1,192)
    const int*   code  = (const int*)d_in[2];     // (2,2048)
    const float* embed = (const float*)d_in[3];   // (6561,512)
    const float* W     = (const float*)d_in[4];   // (1216,1024)
    const float* bvec  = (const float*)d_in[5];   // (1024,)

    float* out  = (float*)d_out;
    float* out0 = out + OUT0_OFF;
    float* out1 = out + OUT1_OFF;
    float* out2 = out + OUT2_OFF;

    float* bias = (float*)d_ws;                                  // 2048 f32 = 8 KB
    unsigned short* Wt = (unsigned short*)((char*)d_ws + 8192);  // 1024x512 bf16 = 1 MB

    bias_kernel<<<8, 256, 0, stream>>>(cond, spk, W, bvec, bias);
    transpose_kernel<<<dim3(16, 32), 256, 0, stream>>>(W, Wt);
    rope_kernel<<<1024, 256, 0, stream>>>(out1);
    mask_kernel<<<2048, 256, 0, stream>>>(out2);
    gemm_kernel<<<dim3(32, 8), 256, 0, stream>>>(embed, code, Wt, bias, out0);
}

// Round 9
// 151.158 us; speedup vs baseline: 1.5617x; 1.5617x over previous
//
#include <hip/hip_runtime.h>
#include <hip/hip_bf16.h>
#include <cstdint>

typedef short short8 __attribute__((ext_vector_type(8)));
typedef float f32x4 __attribute__((ext_vector_type(4)));

#define OUT0_SZ  (2*4096*1024)       // 8388608
#define OUT1_OFF OUT0_SZ             // 8388608
#define OUT1_SZ  (2*4096*64)         // 524288
#define OUT2_OFF (OUT0_SZ + OUT1_SZ) // 8912896

__device__ __forceinline__ unsigned short f2bf(float f) {
    unsigned u = __float_as_uint(f);
    unsigned r = (u + 0x7FFFu + ((u >> 16) & 1u)) >> 16;
    return (unsigned short)r;
}

// ---------------------------------------------------------------------------
// Kernel 1: bias[b][d] = b[d] + cond[b]@W_cond + spk[b]@W_spk
// Split-K in-block: 64 blocks x 256 thr = (2 b x 32 d-chunks) x (8-way ksplit
// x 32 d). LDS tree reduce. Fixes round-2's 92us latency-bound serial version.
// ---------------------------------------------------------------------------
__global__ __launch_bounds__(256) void bias_kernel(
    const float* __restrict__ cond, const float* __restrict__ spk,
    const float* __restrict__ W, const float* __restrict__ bvec,
    float* __restrict__ bias)
{
    __shared__ float red[8][32];
    const int b  = blockIdx.x >> 5;
    const int d0 = (blockIdx.x & 31) * 32;
    const int dl = threadIdx.x & 31;
    const int ks = threadIdx.x >> 5;   // 0..7
    const int d  = d0 + dl;
    const float* condb = cond + b * 512;
    const float* spkb  = spk + b * 192;
    float acc = 0.f;
    #pragma unroll 8
    for (int i = 0; i < 64; ++i) {       // cond rows: 8 x 64 = 512
        int k = ks * 64 + i;
        acc = fmaf(condb[k], W[(size_t)k * 1024 + d], acc);
    }
    #pragma unroll 8
    for (int i = 0; i < 24; ++i) {       // spk rows: 8 x 24 = 192 (W rows 1024+)
        int s = ks * 24 + i;
        acc = fmaf(spkb[s], W[(size_t)(1024 + s) * 1024 + d], acc);
    }
    red[ks][dl] = acc;
    __syncthreads();
    if (ks == 0) {
        float t = acc + bvec[d];
        #pragma unroll
        for (int j = 1; j < 8; ++j) t += red[j][dl];
        bias[b * 1024 + d] = t;
    }
}

// ---------------------------------------------------------------------------
// Kernel 2: pre-gather embedding rows to bf16: Ag[m][k] = bf16(embed[code[m]][k])
// Does gather + f32->bf16 ONCE (vs 8x per-bn inside gemm). 262144 threads.
// ---------------------------------------------------------------------------
__global__ __launch_bounds__(256) void gather_kernel(
    const float* __restrict__ embed, const int* __restrict__ code,
    unsigned short* __restrict__ Ag)
{
    int gtid = blockIdx.x * 256 + threadIdx.x;  // 0..262143
    int r = gtid >> 6;           // 0..4095
    int c = (gtid & 63) * 8;     // 8 elems per thread
    int cv = code[r];
    const float* s = embed + (size_t)cv * 512 + c;
    float4 f0 = *(const float4*)s;
    float4 f1 = *(const float4*)(s + 4);
    short8 v;
    v[0] = (short)f2bf(f0.x); v[1] = (short)f2bf(f0.y);
    v[2] = (short)f2bf(f0.z); v[3] = (short)f2bf(f0.w);
    v[4] = (short)f2bf(f1.x); v[5] = (short)f2bf(f1.y);
    v[6] = (short)f2bf(f1.z); v[7] = (short)f2bf(f1.w);
    *(short8*)&Ag[(size_t)r * 512 + c] = v;
}

// ---------------------------------------------------------------------------
// Kernel 3: transpose W_code (rows 512..1023 of W) -> Wt bf16 [1024][512]
// ---------------------------------------------------------------------------
__global__ __launch_bounds__(256) void transpose_kernel(
    const float* __restrict__ W, unsigned short* __restrict__ Wt)
{
    __shared__ float tile[32][33];
    int k0 = blockIdx.x * 32;
    int n0 = blockIdx.y * 32;
    int lx = threadIdx.x & 31;
    int ly = threadIdx.x >> 5;
    #pragma unroll
    for (int rr = 0; rr < 32; rr += 8)
        tile[ly + rr][lx] = W[(size_t)(512 + k0 + ly + rr) * 1024 + n0 + lx];
    __syncthreads();
    #pragma unroll
    for (int rr = 0; rr < 32; rr += 8)
        Wt[(size_t)(n0 + ly + rr) * 512 + k0 + lx] = f2bf(tile[lx][ly + rr]);
}

// ---------------------------------------------------------------------------
// Kernel 4: fused rope + mask (disjoint output ranges, one launch).
// rope: out1[c][t][2k]=out1[c][t][2k+1]=cos/sin(t*theta_k)  (f64 for accuracy)
// mask: out2[i*4096+j] = (float)(j/24 - i/24), float4 stores
// ---------------------------------------------------------------------------
__global__ __launch_bounds__(256) void rope_mask_kernel(
    float* __restrict__ out1, float* __restrict__ out2)
{
    int tid = blockIdx.x * 256 + threadIdx.x;
    if (tid < 262144) {
        int kk = tid & 31;
        int t  = (tid >> 5) & 4095;
        int c  = tid >> 17;
        double theta = exp2(-(double)kk * 0.41524101186092028); // 10000^(-k/32)
        double a = (double)t * theta;
        float vf = (float)(c ? sin(a) : cos(a));
        float2 w; w.x = vf; w.y = vf;
        *(float2*)&out1[(size_t)(c * 4096 + t) * 64 + kk * 2] = w;
    } else {
        int q = tid - 262144;            // 0..4194303 float4 units
        int i = q >> 10;
        int j = (q & 1023) << 2;
        int bi = i / 24;
        float4 v;
        v.x = (float)((j    ) / 24 - bi);
        v.y = (float)((j + 1) / 24 - bi);
        v.z = (float)((j + 2) / 24 - bi);
        v.w = (float)((j + 3) / 24 - bi);
        ((float4*)out2)[q] = v;
    }
}

// ---------------------------------------------------------------------------
// Kernel 5: GEMM. out0[(b,2u)][n] = out0[(b,2u+1)][n] = Ag[m] @ Wt[n] + bias[b][n]
// M=4096, N=1024, K=512. 128x128 tile, BK=64, 4 waves 2x2, 16x16x32 bf16 MFMA,
// XOR-swizzled LDS (T2). A and B staging both pure short8 loads now.
// ---------------------------------------------------------------------------
__global__ __launch_bounds__(256) void gemm_kernel(
    const unsigned short* __restrict__ Ag, const unsigned short* __restrict__ Wt,
    const float* __restrict__ bias, float* __restrict__ out0)
{
    __shared__ short8 AsV[128 * 64 / 8];
    __shared__ short8 BsV[128 * 64 / 8];
    unsigned short* As = (unsigned short*)AsV;
    unsigned short* Bs = (unsigned short*)BsV;

    const int tid = threadIdx.x;
    const int bm = blockIdx.x;   // 0..31
    const int bn = blockIdx.y;   // 0..7
    const int lane = tid & 63;
    const int wid = tid >> 6;
    const int wr = wid >> 1;
    const int wc = wid & 1;
    const int l15 = lane & 15;
    const int l4  = lane >> 4;

    f32x4 acc[4][4];
    #pragma unroll
    for (int i = 0; i < 4; ++i)
        #pragma unroll
        for (int j = 0; j < 4; ++j)
            acc[i][j] = (f32x4){0.f, 0.f, 0.f, 0.f};

    long a_off[4]; long b_off[4]; int dst[4];
    #pragma unroll
    for (int i = 0; i < 4; ++i) {
        int ch = i * 256 + tid;
        int r  = ch >> 3;
        int kc = (ch & 7) * 8;
        a_off[i] = (long)(bm * 128 + r) * 512 + kc;
        b_off[i] = (long)(bn * 128 + r) * 512 + kc;
        dst[i]   = r * 64 + (kc ^ ((r & 7) << 3));
    }

    for (int kt = 0; kt < 512; kt += 64) {
        __syncthreads();
        #pragma unroll
        for (int i = 0; i < 4; ++i)
            *(short8*)&As[dst[i]] = *(const short8*)&Ag[a_off[i] + kt];
        #pragma unroll
        for (int i = 0; i < 4; ++i)
            *(short8*)&Bs[dst[i]] = *(const short8*)&Wt[b_off[i] + kt];
        __syncthreads();
        #pragma unroll
        for (int ks = 0; ks < 2; ++ks) {
            const int kb = ks * 32 + l4 * 8;
            short8 af[4], bf[4];
            #pragma unroll
            for (int mi = 0; mi < 4; ++mi) {
                int r = wr * 64 + mi * 16 + l15;
                af[mi] = *(const short8*)&As[r * 64 + (kb ^ ((r & 7) << 3))];
            }
            #pragma unroll
            for (int ni = 0; ni < 4; ++ni) {
                int n = wc * 64 + ni * 16 + l15;
                bf[ni] = *(const short8*)&Bs[n * 64 + (kb ^ ((n & 7) << 3))];
            }
            #pragma unroll
            for (int mi = 0; mi < 4; ++mi)
                #pragma unroll
                for (int ni = 0; ni < 4; ++ni)
                    acc[mi][ni] = __builtin_amdgcn_mfma_f32_16x16x32_bf16(
                        af[mi], bf[ni], acc[mi][ni], 0, 0, 0);
        }
    }

    // Epilogue: C/D layout col=lane&15, row=(lane>>4)*4+j. Row m -> t=2u,2u+1.
    const int b = bm >> 4;
    const float* biasb = bias + b * 1024;
    #pragma unroll
    for (int ni = 0; ni < 4; ++ni) {
        const int n = bn * 128 + wc * 64 + ni * 16 + l15;
        const float bv = biasb[n];
        #pragma unroll
        for (int mi = 0; mi < 4; ++mi) {
            const int mbase = bm * 128 + wr * 64 + mi * 16 + l4 * 4;
            #pragma unroll
            for (int j = 0; j < 4; ++j) {
                const int u = (mbase + j) & 2047;
                const size_t o = ((size_t)(b * 4096 + 2 * u)) * 1024 + n;
                const float v = acc[mi][ni][j] + bv;
                out0[o] = v;
                out0[o + 1024] = v;
            }
        }
    }
}

// ---------------------------------------------------------------------------
extern "C" void kernel_launch(void* const* d_in, const int* in_sizes, int n_in,
                              void* d_out, int out_size, void* d_ws, size_t ws_size,
                              hipStream_t stream) {
    const float* cond  = (const float*)d_in[0];
    const float* spk   = (const float*)d_in[1];
    const int*   code  = (const int*)d_in[2];
    const float* embed = (const float*)d_in[3];
    const float* W     = (const float*)d_in[4];
    const float* bvec  = (const float*)d_in[5];

    float* out  = (float*)d_out;
    float* out0 = out;
    float* out1 = out + OUT1_OFF;
    float* out2 = out + OUT2_OFF;

    float* bias = (float*)d_ws;                                   // 8 KB
    unsigned short* Wt = (unsigned short*)((char*)d_ws + 8192);   // 1 MB
    unsigned short* Ag = (unsigned short*)((char*)d_ws + 8192 + 1048576); // 4 MB

    gather_kernel<<<1024, 256, 0, stream>>>(embed, code, Ag);
    bias_kernel<<<64, 256, 0, stream>>>(cond, spk, W, bvec, bias);
    transpose_kernel<<<dim3(16, 32), 256, 0, stream>>>(W, Wt);
    rope_mask_kernel<<<17408, 256, 0, stream>>>(out1, out2);
    gemm_kernel<<<dim3(32, 8), 256, 0, stream>>>(Ag, Wt, bias, out0);
}